// Round 5
// baseline (387.735 us; speedup 1.0000x reference)
//
#include <hip/hip_runtime.h>
#include <hip/hip_bf16.h>

// out[n] = sigmoid( u[n] . W[type_idx[n]] . v[n] ),  N=131072, D=256, K=8
// v4 = v3 + ufrag PINNED in VGPRs via opaque asm identity.
//   Round-4 diagnosis: VGPR_Count=40 proves LLVM rematerialized the U-fragment
//   loads inside the eb-loop (re-reading U 16x from L1/L2 per wave -> latency
//   bound at 9% HBM). asm volatile("":"+v"(x)) makes the fragment origin
//   opaque: it cannot be rematerialized, forcing register residency.

#define N_SAMPLES 131072
#define DIM 256
#define KTYPES 8
#define TILE_M 64
#define MAXTILES (N_SAMPLES / TILE_M + KTYPES)   // 2056

typedef _Float16 f16x8 __attribute__((ext_vector_type(8)));
typedef float f32x4 __attribute__((ext_vector_type(4)));

// ---------------- ws layout ----------------
#define WT_OFF   ((size_t)0)            // 1MB: Wt fp16 [k][e][d]
#define CNT_OFF  ((size_t)0x100000)     // counts[8]  (zeroed)
#define CUR_OFF  ((size_t)0x100020)     // cursors[8] (zeroed)
#define PERM_OFF ((size_t)0x100040)     // perm[N] int

// Pass A: W fp32 [k][d][e] -> Wt fp16 [k][e][d] via LDS 64x64 tile transpose,
// fused with idx histogram (int4 loads).
__global__ __launch_bounds__(256) void prep_kernel(
    const float* __restrict__ W, _Float16* __restrict__ Wt,
    const int* __restrict__ idx, int* __restrict__ counts)
{
    __shared__ float lds[64][68];
    __shared__ int lcnt[KTYPES];
    int t = threadIdx.x;
    if (t < KTYPES) lcnt[t] = 0;
    __syncthreads();

    int b = blockIdx.x;                    // 128 blocks
    int k = b >> 4, tile = b & 15;
    int dt = (tile & 3) * 64, et = (tile >> 2) * 64;

    int r = t >> 2, c0 = (t & 3) * 16;
    const float* src = W + ((size_t)k << 16) + (size_t)(dt + r) * 256 + et + c0;
    float4 x0 = *(const float4*)(src + 0);
    float4 x1 = *(const float4*)(src + 4);
    float4 x2 = *(const float4*)(src + 8);
    float4 x3 = *(const float4*)(src + 12);
    *(float4*)&lds[r][c0 + 0]  = x0;
    *(float4*)&lds[r][c0 + 4]  = x1;
    *(float4*)&lds[r][c0 + 8]  = x2;
    *(float4*)&lds[r][c0 + 12] = x3;

    int4 i4 = ((const int4*)idx)[b * 256 + t];
    atomicAdd(&lcnt[i4.x], 1);
    atomicAdd(&lcnt[i4.y], 1);
    atomicAdd(&lcnt[i4.z], 1);
    atomicAdd(&lcnt[i4.w], 1);
    __syncthreads();

    int e = t >> 2, d0 = (t & 3) * 16;
    f16x8 o0, o1;
    #pragma unroll
    for (int j = 0; j < 8; ++j) o0[j] = (_Float16)lds[d0 + j][e];
    #pragma unroll
    for (int j = 0; j < 8; ++j) o1[j] = (_Float16)lds[d0 + 8 + j][e];
    _Float16* dst = Wt + ((size_t)k << 16) + (size_t)(et + e) * 256 + dt + d0;
    *(f16x8*)(dst + 0) = o0;
    *(f16x8*)(dst + 8) = o1;

    if (t < KTYPES && lcnt[t] > 0) atomicAdd(&counts[t], lcnt[t]);
}

// Pass B: scatter sample ids into per-type contiguous regions of perm.
__global__ __launch_bounds__(1024) void scatter_kernel(
    const int* __restrict__ idx, const int* __restrict__ counts,
    int* __restrict__ cursors, int* __restrict__ perm)
{
    __shared__ int lcnt[KTYPES], lbase[KTYPES];
    int t = threadIdx.x;
    if (t < KTYPES) lcnt[t] = 0;
    __syncthreads();
    int n = blockIdx.x * 1024 + t;         // 128 blocks x 1024
    int k = idx[n];
    int lpos = atomicAdd(&lcnt[k], 1);
    __syncthreads();
    if (t < KTYPES)
        lbase[t] = (lcnt[t] > 0) ? atomicAdd(&cursors[t], lcnt[t]) : 0;
    __syncthreads();
    int gof = 0, off = 0;
    #pragma unroll
    for (int j = 0; j < KTYPES; ++j) {
        int cj = counts[j];
        if (j == k) gof = off;
        off += cj;
    }
    perm[gof + lbase[k] + lpos] = n;
}

// Pass C: main. Block = 64 samples (4 waves x 16). No LDS, no barriers.
// MFMA 16x16x32 computes T^T = (W_k^T)(U^T):
//   A[i][kk]: i = e_local = lane&15, kk = (lane>>4)*8+j  -> Wt[eb*16+lm][dc*32+lq*8+j]
//   B[kk][n]: n = sample  = lane&15, kk = (lane>>4)*8+j  -> U[s_lm][dc*32+lq*8+j]
//   D[i][j] : i = lq*4+r (e), j = lm (sample)
// => lane folds acc with exact fp32 float4 of V[s_lm][eb*16+lq*4 .. +4).
__global__ __launch_bounds__(256, 4) void bilinear_main(
    const float* __restrict__ U, const float* __restrict__ V,
    const _Float16* __restrict__ Wt, const int* __restrict__ perm,
    const int* __restrict__ counts, float* __restrict__ out)
{
    int tblk = blockIdx.x;
    int k = -1, base = 0, gof = 0, cnt = 0;
    {
        int toff = 0, off = 0;
        #pragma unroll
        for (int j = 0; j < KTYPES; ++j) {
            int cj = counts[j];
            int nt = (cj + TILE_M - 1) >> 6;
            if (tblk >= toff && tblk < toff + nt) {
                k = j; base = (tblk - toff) * TILE_M; gof = off; cnt = cj;
            }
            toff += nt; off += cj;
        }
    }
    if (k < 0) return;

    int tid = threadIdx.x;
    int wave = tid >> 6, lane = tid & 63;
    int lq = lane >> 4, lm = lane & 15;

    int row_local = base + wave * 16 + lm;
    bool valid = row_local < cnt;
    int rl = valid ? row_local : (cnt - 1);
    int sm = perm[gof + rl];

    const float* Urow = U + ((size_t)sm << 8);
    const float* Vrow = V + ((size_t)sm << 8);
    const _Float16* Wk = Wt + ((size_t)k << 16);

    // U fragments (B operand), loaded once and PINNED in VGPRs.
    f16x8 ufrag[8];
    #pragma unroll
    for (int dc = 0; dc < 8; ++dc) {
        float4 f0 = *(const float4*)(Urow + dc * 32 + lq * 8);
        float4 f1 = *(const float4*)(Urow + dc * 32 + lq * 8 + 4);
        f16x8 a;
        a[0] = (_Float16)f0.x; a[1] = (_Float16)f0.y;
        a[2] = (_Float16)f0.z; a[3] = (_Float16)f0.w;
        a[4] = (_Float16)f1.x; a[5] = (_Float16)f1.y;
        a[6] = (_Float16)f1.z; a[7] = (_Float16)f1.w;
        asm volatile("" : "+v"(a));   // opaque: cannot be rematerialized
        ufrag[dc] = a;
    }

    // V pipeline: 2-deep manual rotation (static names -> registers)
    float4 vcur = *(const float4*)(Vrow + 0 * 16 + lq * 4);
    float4 vnxt = *(const float4*)(Vrow + 1 * 16 + lq * 4);
    float spart = 0.f;

    #pragma unroll 2
    for (int eb = 0; eb < 16; ++eb) {
        const _Float16* ap = Wk + ((size_t)(eb * 16 + lm) << 8) + lq * 8;
        f32x4 acc = {0.f, 0.f, 0.f, 0.f};
        #pragma unroll
        for (int dc = 0; dc < 8; ++dc) {
            f16x8 a = *(const f16x8*)(ap + dc * 32);
            acc = __builtin_amdgcn_mfma_f32_16x16x32_f16(a, ufrag[dc], acc, 0, 0, 0);
        }
        float4 vuse = vcur;
        vcur = vnxt;
        int ebn = (eb + 2 < 16) ? (eb + 2) : 0;      // clamped prefetch
        vnxt = *(const float4*)(Vrow + ebn * 16 + lq * 4);
        spart += acc[0] * vuse.x + acc[1] * vuse.y + acc[2] * vuse.z + acc[3] * vuse.w;
    }

    // reduce across lq (lane bits 4,5)
    spart += __shfl_xor(spart, 16);
    spart += __shfl_xor(spart, 32);

    if (lq == 0 && valid)
        out[sm] = 1.0f / (1.0f + __expf(-spart));
}

extern "C" void kernel_launch(void* const* d_in, const int* in_sizes, int n_in,
                              void* d_out, int out_size, void* d_ws, size_t ws_size,
                              hipStream_t stream) {
    const float* U = (const float*)d_in[0];
    const float* V = (const float*)d_in[1];
    const float* W = (const float*)d_in[2];
    const int* idx = (const int*)d_in[3];
    float* out = (float*)d_out;
    char* ws = (char*)d_ws;

    _Float16* Wt = (_Float16*)(ws + WT_OFF);
    int* counts  = (int*)(ws + CNT_OFF);
    int* cursors = (int*)(ws + CUR_OFF);
    int* perm    = (int*)(ws + PERM_OFF);

    hipMemsetAsync(ws + CNT_OFF, 0, 64, stream);            // counts + cursors
    prep_kernel<<<128, 256, 0, stream>>>(W, Wt, idx, counts);
    scatter_kernel<<<128, 1024, 0, stream>>>(idx, counts, cursors, perm);
    bilinear_main<<<MAXTILES, 256, 0, stream>>>(U, V, Wt, perm, counts, out);
}